// Round 2
// baseline (69.534 us; speedup 1.0000x reference)
//
#include <hip/hip_runtime.h>
#include <math.h>

#define KCOMP 1024
#define DDIM  6
#define BPTS  16384

#define PTS    64            // points per block (4 MFMA pt-tiles of 16)
#define NWAVE  16            // waves per block; wave w owns comps [w*64, w*64+64)
#define NTPW   4             // n-tiles per wave (4 x 16 = 64 comps)

#define WFLAG_MAGIC 0x1B7A3C5Fu   // non-byte-repeat: cannot collide with memset poison

typedef __attribute__((ext_vector_type(8))) short bf16x8;  // 8 bf16 = 4 VGPRs
typedef __attribute__((ext_vector_type(4))) float f32x4;

// self-contained bf16 helpers (RNE)
__device__ __forceinline__ unsigned short f32_to_bf16(float f) {
    unsigned int u = __float_as_uint(f);
    u += 0x7fffu + ((u >> 16) & 1u);
    return (unsigned short)(u >> 16);
}
__device__ __forceinline__ float bf16_to_f32(unsigned short h) {
    return __uint_as_float(((unsigned int)h) << 16);
}

// Sum across each row of 16 lanes via DPP rotate-adds (VALU pipe).
__device__ __forceinline__ float row16_sum(float v) {
    int t;
    t = __builtin_amdgcn_update_dpp(0, __float_as_int(v), 0x121, 0xf, 0xf, false); // row_ror:1
    v += __int_as_float(t);
    t = __builtin_amdgcn_update_dpp(0, __float_as_int(v), 0x122, 0xf, 0xf, false); // row_ror:2
    v += __int_as_float(t);
    t = __builtin_amdgcn_update_dpp(0, __float_as_int(v), 0x124, 0xf, 0xf, false); // row_ror:4
    v += __int_as_float(t);
    t = __builtin_amdgcn_update_dpp(0, __float_as_int(v), 0x128, 0xf, 0xf, false); // row_ror:8
    v += __int_as_float(t);
    return v;
}

// ---------------------------------------------------------------------------
// R2: single dispatch, NON-redundant precompute via device-scope flag handshake.
//   R1 post-mortem: fusing with per-block redundancy cost +2 us (256x Cholesky);
//   the dispatch gap it saved was ~0-1 us. This version keeps one dispatch but
//   computes W exactly once: blocks 0..15, wave 0, lane l -> comp b*64+l (the
//   R5 precompute verbatim), W written to workspace global memory.
// Handshake (deadlock-free, no co-residency assumption: writers never wait):
//   writer wave: store W -> fence(release, agent)  [wave-level s_waitcnt +
//   buffer_wbl2 covers all 64 lanes' stores since ONE wave writes all 64
//   comps] -> flags[b] = MAGIC (agent-scope atomic store).
//   reader: wave 0 of every block spins on the 16 flags (relaxed agent-scope
//   atomic loads, one 64B line, s_sleep-throttled), acquire-fence, then
//   __syncthreads releases the block. Kernel-start acquire already wiped all
//   L2s, and nothing reads W addresses before the flag check, so no stale
//   lines are possible; the acquire fence gives the ordering.
// Poison semantics: the harness memset re-arms flags each iteration; MAGIC is
//   not a repeated-byte pattern so poison can never equal it. A stale-MAGIC
//   replay (no re-poison) is benign: W is idempotent across iterations
//   (same inputs -> identical bytes), so early readers see identical data.
// Overlap: all 256 blocks run their x-load + A-fragment build while the 16
//   writer waves do the Cholesky chain -> precompute latency mostly hidden.
// LDS: 12.3 KB (fragA 8 KB + partial 4 KB). VGPR cap 128 (launch_bounds 1024,4).
// ---------------------------------------------------------------------------
__global__ __launch_bounds__(1024, 4) void gmm_fused(
        const float* __restrict__ x,
        const float* __restrict__ means,
        const float* __restrict__ covs,
        const float* __restrict__ weights,
        unsigned int* __restrict__ flags,    // [16] in workspace
        unsigned short* __restrict__ Wh,     // [32768] in workspace
        unsigned short* __restrict__ Wl,     // [32768] in workspace
        float* __restrict__ out) {
    const int tid  = threadIdx.x;
    const int lane = tid & 63;
    const int w    = __builtin_amdgcn_readfirstlane(tid >> 6);  // 0..15
    const int quad = lane >> 4;                                  // 0..3
    const int m15  = lane & 15;
    const int pbase = blockIdx.x * PTS;

    __shared__ bf16x8 fragA[8][64];          // [split*4+pt][lane], 8 KB
    __shared__ float  partial[NWAVE][PTS];   // 4 KB

    // ---- producer waves: build one (pt, split) A-fragment set, store now ----
    if (w < 8) {
        const int pt    = w & 3;
        const int split = w >> 2;            // 0 = hi, 1 = lo
        float v[6];
        const float* xp = x + (pbase + pt * 16 + m15) * 6;
        #pragma unroll
        for (int i = 0; i < 6; i++) v[i] = xp[i];

        float f[8];
        if (quad == 0) {
            f[0]=v[0]*v[0]; f[1]=v[0]*v[1]; f[2]=v[0]*v[2]; f[3]=v[0]*v[3];
            f[4]=v[0]*v[4]; f[5]=v[0]*v[5]; f[6]=v[1]*v[1]; f[7]=v[1]*v[2];
        } else if (quad == 1) {
            f[0]=v[1]*v[3]; f[1]=v[1]*v[4]; f[2]=v[1]*v[5]; f[3]=v[2]*v[2];
            f[4]=v[2]*v[3]; f[5]=v[2]*v[4]; f[6]=v[2]*v[5]; f[7]=v[3]*v[3];
        } else if (quad == 2) {
            f[0]=v[3]*v[4]; f[1]=v[3]*v[5]; f[2]=v[4]*v[4]; f[3]=v[4]*v[5];
            f[4]=v[5]*v[5]; f[5]=v[0];      f[6]=v[1];      f[7]=v[2];
        } else {
            f[0]=v[3]; f[1]=v[4]; f[2]=v[5]; f[3]=1.0f;
            f[4]=0.0f; f[5]=0.0f; f[6]=0.0f; f[7]=0.0f;
        }

        bf16x8 frag;
        #pragma unroll
        for (int j = 0; j < 8; j++) {
            unsigned short h = f32_to_bf16(f[j]);
            frag[j] = (split == 0) ? (short)h
                                   : (short)f32_to_bf16(f[j] - bf16_to_f32(h));
        }
        fragA[w][lane] = frag;               // frag regs dead before precompute
    }

    // ---- writer waves: blocks 0..15, wave 0 -> comps [b*64, b*64+64) ----
    if (blockIdx.x < 16 && w == 0) {
        const int k = blockIdx.x * 64 + lane;
        float A[6][6];
        {
            const f32x4* C4 = (const f32x4*)(covs + k * 36);   // 144B, 16B aligned
            float cf[36];
            #pragma unroll
            for (int q = 0; q < 9; q++) {
                f32x4 t4 = C4[q];
                #pragma unroll
                for (int e = 0; e < 4; e++) cf[q * 4 + e] = t4[e];
            }
            #pragma unroll
            for (int i = 0; i < 6; i++)
                #pragma unroll
                for (int j = 0; j < 6; j++)
                    A[i][j] = cf[i * 6 + j];
        }

        // In-place Cholesky: lower triangle of A becomes L. Track diag product.
        float dprod = 1.0f;
        #pragma unroll
        for (int j = 0; j < 6; j++) {
            float d = A[j][j];
            #pragma unroll
            for (int t = 0; t < 6; t++) if (t < j) d -= A[j][t] * A[j][t];
            float ljj = __builtin_amdgcn_sqrtf(d);
            dprod *= ljj;
            A[j][j] = ljj;
            float inv = __builtin_amdgcn_rcpf(ljj);
            #pragma unroll
            for (int i = 0; i < 6; i++) {
                if (i > j) {
                    float s = A[i][j];
                    #pragma unroll
                    for (int t = 0; t < 6; t++) if (t < j) s -= A[i][t] * A[j][t];
                    A[i][j] = s * inv;
                }
            }
        }
        float logdet2 = 2.0f * __builtin_amdgcn_logf(dprod);   // log2(det Sigma)

        // Li = L^{-1} (lower)
        float Li[6][6];
        #pragma unroll
        for (int j = 0; j < 6; j++) {
            Li[j][j] = __builtin_amdgcn_rcpf(A[j][j]);
            #pragma unroll
            for (int i = 0; i < 6; i++) {
                if (i > j) {
                    float s = 0.0f;
                    #pragma unroll
                    for (int t = 0; t < 6; t++) if (t >= j && t < i) s += A[i][t] * Li[t][j];
                    Li[i][j] = -s * __builtin_amdgcn_rcpf(A[i][i]);
                }
            }
        }

        // P = Li^T Li -> overwrite A
        #pragma unroll
        for (int i = 0; i < 6; i++) {
            #pragma unroll
            for (int j = 0; j < 6; j++) {
                if (j >= i) {
                    float s = 0.0f;
                    int lo = (i > j) ? i : j;
                    #pragma unroll
                    for (int t = 0; t < 6; t++) if (t >= lo) s += Li[t][i] * Li[t][j];
                    A[i][j] = s;
                    A[j][i] = s;
                }
            }
        }

        const float* mu = means + k * 6;
        float m[6];
        #pragma unroll
        for (int i = 0; i < 6; i++) m[i] = mu[i];

        float b[6];
        float muPmu = 0.0f;
        #pragma unroll
        for (int i = 0; i < 6; i++) {
            float s = 0.0f;
            #pragma unroll
            for (int j = 0; j < 6; j++) s += A[i][j] * m[j];
            b[i] = s;
            muPmu += s * m[i];
        }

        const float LOG2_2PI = 2.6514961294723187f;   // log2(2*pi)
        const float LOG2E    = 1.4426950408889634f;
        float c2 = __builtin_amdgcn_logf(weights[k])
                 - 0.5f * (6.0f * LOG2_2PI + logdet2)
                 - 0.5f * LOG2E * muPmu;

        float wv[32];
        int t = 0;
        #pragma unroll
        for (int i = 0; i < 6; i++)
            #pragma unroll
            for (int j = 0; j < 6; j++)
                if (j >= i) wv[t++] = LOG2E * ((i == j) ? -0.5f * A[i][j] : -A[i][j]);
        #pragma unroll
        for (int i = 0; i < 6; i++) wv[t++] = LOG2E * b[i];
        wv[27] = c2;
        wv[28] = 0.0f; wv[29] = 0.0f; wv[30] = 0.0f; wv[31] = 0.0f;

        // store split-bf16 W in B-fragment order (same indexing as R5)
        int ntile = k >> 4, n15 = k & 15;
        #pragma unroll
        for (int kk = 0; kk < 32; kk++) {
            float v = wv[kk];
            unsigned short h = f32_to_bf16(v);
            unsigned short l = f32_to_bf16(v - bf16_to_f32(h));
            int idx = ((ntile * 64) + ((kk >> 3) << 4) + n15) * 8 + (kk & 7);
            Wh[idx] = h;
            Wl[idx] = l;
        }

        // publish: flush this wave's stores to device scope, then set flag
        __builtin_amdgcn_fence(__ATOMIC_RELEASE, "agent");
        if (lane == 0)
            __hip_atomic_store(&flags[blockIdx.x], WFLAG_MAGIC,
                               __ATOMIC_RELAXED, __HIP_MEMORY_SCOPE_AGENT);
    }

    __syncthreads();                         // fragA visible to all waves

    bf16x8 Ah[4], Al[4];
    #pragma unroll
    for (int pt = 0; pt < 4; pt++) {
        Ah[pt] = fragA[pt][lane];
        Al[pt] = fragA[4 + pt][lane];
    }

    // ---- wave 0 waits for all 16 W-writer flags; barrier releases block ----
    if (w == 0) {
        while (true) {
            unsigned int v = __hip_atomic_load(&flags[m15], __ATOMIC_RELAXED,
                                               __HIP_MEMORY_SCOPE_AGENT);
            if (__all(v == WFLAG_MAGIC)) break;
            __builtin_amdgcn_s_sleep(2);
        }
        __builtin_amdgcn_fence(__ATOMIC_ACQUIRE, "agent");
    }
    __syncthreads();                         // orders every wave after the acquire

    // ---- MFMA loop over this wave's 4 n-tiles (global W loads, R0 style) ----
    const bf16x8* WhF = (const bf16x8*)Wh + (w * NTPW) * 64;
    const bf16x8* WlF = (const bf16x8*)Wl + (w * NTPW) * 64;

    float esum[4][4];
    #pragma unroll
    for (int pt = 0; pt < 4; pt++)
        #pragma unroll
        for (int r = 0; r < 4; r++) esum[pt][r] = 0.0f;

    #pragma unroll
    for (int t = 0; t < NTPW; t++) {
        bf16x8 bh = WhF[t * 64 + lane];
        bf16x8 bl = WlF[t * 64 + lane];
        #pragma unroll
        for (int pt = 0; pt < 4; pt++) {
            f32x4 c = {0.0f, 0.0f, 0.0f, 0.0f};
            c = __builtin_amdgcn_mfma_f32_16x16x32_bf16(Ah[pt], bh, c, 0, 0, 0);
            c = __builtin_amdgcn_mfma_f32_16x16x32_bf16(Al[pt], bh, c, 0, 0, 0);
            c = __builtin_amdgcn_mfma_f32_16x16x32_bf16(Ah[pt], bl, c, 0, 0, 0);
            #pragma unroll
            for (int r = 0; r < 4; r++)
                esum[pt][r] += __builtin_amdgcn_exp2f(c[r]);
        }
    }

    // ---- reduce over the 16 comp-lanes (DPP row_ror rotate-adds) ----
    #pragma unroll
    for (int pt = 0; pt < 4; pt++)
        #pragma unroll
        for (int r = 0; r < 4; r++)
            esum[pt][r] = row16_sum(esum[pt][r]);

    if (m15 == 0) {
        #pragma unroll
        for (int pt = 0; pt < 4; pt++)
            #pragma unroll
            for (int r = 0; r < 4; r++)
                partial[w][pt * 16 + quad * 4 + r] = esum[pt][r];
    }
    __syncthreads();

    if (tid < PTS) {
        float S = 0.0f;
        #pragma unroll
        for (int c = 0; c < NWAVE; c++) S += partial[c][tid];
        const float LN2 = 0.6931471805599453f;
        out[pbase + tid] = LN2 * __builtin_amdgcn_logf(S);  // v_log_f32 = log2
    }
}

extern "C" void kernel_launch(void* const* d_in, const int* in_sizes, int n_in,
                              void* d_out, int out_size, void* d_ws, size_t ws_size,
                              hipStream_t stream) {
    const float* x       = (const float*)d_in[0];  // [B, 6]
    const float* means   = (const float*)d_in[1];  // [K, 6]
    const float* covs    = (const float*)d_in[2];  // [K, 6, 6]
    const float* weights = (const float*)d_in[3];  // [K]
    float* out = (float*)d_out;                    // [B]

    unsigned int*   flags = (unsigned int*)d_ws;                     // 16 x u32
    unsigned short* Wh    = (unsigned short*)((char*)d_ws + 256);    // 64 KB
    unsigned short* Wl    = Wh + 32768;                              // 64 KB

    gmm_fused<<<BPTS / PTS, 1024, 0, stream>>>(x, means, covs, weights,
                                               flags, Wh, Wl, out);
}

// Round 3
// 65.885 us; speedup vs baseline: 1.0554x; 1.0554x over previous
//
#include <hip/hip_runtime.h>
#include <math.h>

#define KCOMP 1024
#define DDIM  6
#define BPTS  16384

#define PTS    64            // points per block (4 MFMA pt-tiles of 16)
#define NWAVE  16            // waves per block; wave w owns comps [w*64, w*64+64)
#define NTPW   4             // n-tiles per wave (4 x 16 = 64 comps)

typedef __attribute__((ext_vector_type(8))) short bf16x8;  // 8 bf16 = 4 VGPRs
typedef __attribute__((ext_vector_type(4))) float f32x4;

// self-contained bf16 helpers (RNE)
__device__ __forceinline__ unsigned short f32_to_bf16(float f) {
    unsigned int u = __float_as_uint(f);
    u += 0x7fffu + ((u >> 16) & 1u);
    return (unsigned short)(u >> 16);
}
__device__ __forceinline__ float bf16_to_f32(unsigned short h) {
    return __uint_as_float(((unsigned int)h) << 16);
}

// Sum across each row of 16 lanes via DPP rotate-adds (VALU pipe).
__device__ __forceinline__ float row16_sum(float v) {
    int t;
    t = __builtin_amdgcn_update_dpp(0, __float_as_int(v), 0x121, 0xf, 0xf, false); // row_ror:1
    v += __int_as_float(t);
    t = __builtin_amdgcn_update_dpp(0, __float_as_int(v), 0x122, 0xf, 0xf, false); // row_ror:2
    v += __int_as_float(t);
    t = __builtin_amdgcn_update_dpp(0, __float_as_int(v), 0x124, 0xf, 0xf, false); // row_ror:4
    v += __int_as_float(t);
    t = __builtin_amdgcn_update_dpp(0, __float_as_int(v), 0x128, 0xf, 0xf, false); // row_ror:8
    v += __int_as_float(t);
    return v;
}

// ---------------------------------------------------------------------------
// Kernel 1 (R3): per-component precompute via 3x3-block SCHUR-COMPLEMENT
// inverse instead of Cholesky (R0-R2 post-mortem: the two-dispatch R0
// structure is optimal — fusion variants both regressed because the dispatch
// gap is ~0 under graph capture; the only slack left is THIS kernel's serial
// dependency chain, run by just 16 waves).
//   Sigma = [[A,B],[B^T,C]] (3x3 blocks). A^{-1}, S^{-1} = (C - B^T A^{-1} B)^{-1}
//   via symmetric cofactor/adjugate: ~220 nearly-independent flops, only two
//   v_rcp on the critical path, no sqrt recursion (Cholesky chain was ~6
//   dependent sqrt->rcp->update steps + triangular inverse).
//   logdet2 = log2(detA) + log2(detS); both dets > 0 (lambda_min >= 0.1).
// W packing / fragment order identical to R0:
//   W[0..20,k]  = log2e * (-0.5*P_ii diag / -P_ij offdiag)   (Z: x_i x_j, i<=j)
//   W[21..26,k] = log2e * (P mu)_i
//   W[27,k]     = log2(w) - 0.5*(6*log2(2pi) + logdet2) - 0.5*log2e*mu^T P mu
//   W[28..31,k] = 0
//   idx(n,k) = ((n>>4)*64 + ((k>>3)<<4) + (n&15))*8 + (k&7)
// W store vectorized: each group of 8 consecutive kk is contiguous -> b128.
// ---------------------------------------------------------------------------
__global__ __launch_bounds__(64, 1) void gmm_precompute(
        const float* __restrict__ means,
        const float* __restrict__ covs,
        const float* __restrict__ weights,
        unsigned short* __restrict__ Wh,     // [32768]
        unsigned short* __restrict__ Wl) {   // [32768]
    int k = blockIdx.x * 64 + threadIdx.x;
    if (k >= KCOMP) return;

    float Sg[36];
    {
        const f32x4* C4 = (const f32x4*)(covs + k * 36);   // 144 B, 16B aligned
        #pragma unroll
        for (int q = 0; q < 9; q++) {
            f32x4 t4 = C4[q];
            #pragma unroll
            for (int e = 0; e < 4; e++) Sg[q * 4 + e] = t4[e];
        }
    }
#define SG(i, j) Sg[(i) * 6 + (j)]

    // ---- A^{-1} (symmetric 3x3 cofactor inverse) ----
    const float A00 = SG(0,0), A01 = SG(0,1), A02 = SG(0,2);
    const float A11 = SG(1,1), A12 = SG(1,2), A22 = SG(2,2);
    float a00 = A11 * A22 - A12 * A12;
    float a01 = A02 * A12 - A01 * A22;
    float a02 = A01 * A12 - A02 * A11;
    float a11 = A00 * A22 - A02 * A02;
    float a12 = A01 * A02 - A00 * A12;
    float a22 = A00 * A11 - A01 * A01;
    float detA = A00 * a00 + A01 * a01 + A02 * a02;
    float rdA  = __builtin_amdgcn_rcpf(detA);
    float Ai[3][3];
    Ai[0][0] = a00 * rdA; Ai[0][1] = a01 * rdA; Ai[0][2] = a02 * rdA;
    Ai[1][0] = a01 * rdA; Ai[1][1] = a11 * rdA; Ai[1][2] = a12 * rdA;
    Ai[2][0] = a02 * rdA; Ai[2][1] = a12 * rdA; Ai[2][2] = a22 * rdA;

    // B[i][j] = Sg[i][3+j]
    float Bm[3][3];
    #pragma unroll
    for (int i = 0; i < 3; i++)
        #pragma unroll
        for (int j = 0; j < 3; j++)
            Bm[i][j] = SG(i, 3 + j);

    // M = A^{-1} B
    float M[3][3];
    #pragma unroll
    for (int i = 0; i < 3; i++)
        #pragma unroll
        for (int j = 0; j < 3; j++)
            M[i][j] = Ai[i][0] * Bm[0][j] + Ai[i][1] * Bm[1][j] + Ai[i][2] * Bm[2][j];

    // S = C - B^T M (symmetric; upper entries)
    float S00 = SG(3,3) - (Bm[0][0]*M[0][0] + Bm[1][0]*M[1][0] + Bm[2][0]*M[2][0]);
    float S01 = SG(3,4) - (Bm[0][0]*M[0][1] + Bm[1][0]*M[1][1] + Bm[2][0]*M[2][1]);
    float S02 = SG(3,5) - (Bm[0][0]*M[0][2] + Bm[1][0]*M[1][2] + Bm[2][0]*M[2][2]);
    float S11 = SG(4,4) - (Bm[0][1]*M[0][1] + Bm[1][1]*M[1][1] + Bm[2][1]*M[2][1]);
    float S12 = SG(4,5) - (Bm[0][1]*M[0][2] + Bm[1][1]*M[1][2] + Bm[2][1]*M[2][2]);
    float S22 = SG(5,5) - (Bm[0][2]*M[0][2] + Bm[1][2]*M[1][2] + Bm[2][2]*M[2][2]);

    // ---- S^{-1} (symmetric 3x3 cofactor inverse) ----
    float s00 = S11 * S22 - S12 * S12;
    float s01 = S02 * S12 - S01 * S22;
    float s02 = S01 * S12 - S02 * S11;
    float s11 = S00 * S22 - S02 * S02;
    float s12 = S01 * S02 - S00 * S12;
    float s22 = S00 * S11 - S01 * S01;
    float detS = S00 * s00 + S01 * s01 + S02 * s02;
    float rdS  = __builtin_amdgcn_rcpf(detS);
    float Si[3][3];
    Si[0][0] = s00 * rdS; Si[0][1] = s01 * rdS; Si[0][2] = s02 * rdS;
    Si[1][0] = s01 * rdS; Si[1][1] = s11 * rdS; Si[1][2] = s12 * rdS;
    Si[2][0] = s02 * rdS; Si[2][1] = s12 * rdS; Si[2][2] = s22 * rdS;

    // logdet2 = log2(det Sigma) = log2(detA) + log2(detS)
    float logdet2 = __builtin_amdgcn_logf(detA) + __builtin_amdgcn_logf(detS);

    // N = M S^{-1}
    float N[3][3];
    #pragma unroll
    for (int i = 0; i < 3; i++)
        #pragma unroll
        for (int j = 0; j < 3; j++)
            N[i][j] = M[i][0] * Si[0][j] + M[i][1] * Si[1][j] + M[i][2] * Si[2][j];

    // P = Sigma^{-1}:
    //   TL = A^{-1} + N M^T, TR = -N, BR = S^{-1}   (symmetrized via mirror)
    float P[6][6];
    #pragma unroll
    for (int i = 0; i < 3; i++) {
        #pragma unroll
        for (int j = 0; j < 3; j++) {
            if (j >= i) {
                float v = Ai[i][j] + (N[i][0]*M[j][0] + N[i][1]*M[j][1] + N[i][2]*M[j][2]);
                P[i][j] = v; P[j][i] = v;
            }
        }
    }
    #pragma unroll
    for (int i = 0; i < 3; i++)
        #pragma unroll
        for (int j = 0; j < 3; j++) {
            float v = -N[i][j];
            P[i][3 + j] = v; P[3 + j][i] = v;
        }
    #pragma unroll
    for (int i = 0; i < 3; i++)
        #pragma unroll
        for (int j = 0; j < 3; j++)
            if (j >= i) { P[3 + i][3 + j] = Si[i][j]; P[3 + j][3 + i] = Si[i][j]; }

    const float* mu = means + k * 6;
    float m[6];
    #pragma unroll
    for (int i = 0; i < 6; i++) m[i] = mu[i];

    float b[6];
    float muPmu = 0.0f;
    #pragma unroll
    for (int i = 0; i < 6; i++) {
        float s = 0.0f;
        #pragma unroll
        for (int j = 0; j < 6; j++) s += P[i][j] * m[j];
        b[i] = s;
        muPmu += s * m[i];
    }

    const float LOG2_2PI = 2.6514961294723187f;   // log2(2*pi)
    const float LOG2E    = 1.4426950408889634f;
    float c2 = __builtin_amdgcn_logf(weights[k])
             - 0.5f * (6.0f * LOG2_2PI + logdet2)
             - 0.5f * LOG2E * muPmu;

    float wv[32];
    int t = 0;
    #pragma unroll
    for (int i = 0; i < 6; i++)
        #pragma unroll
        for (int j = 0; j < 6; j++)
            if (j >= i) wv[t++] = LOG2E * ((i == j) ? -0.5f * P[i][j] : -P[i][j]);
    #pragma unroll
    for (int i = 0; i < 6; i++) wv[t++] = LOG2E * b[i];
    wv[27] = c2;
    wv[28] = 0.0f; wv[29] = 0.0f; wv[30] = 0.0f; wv[31] = 0.0f;

    // vectorized W store: group g holds kk = g*8..g*8+7, contiguous shorts
    int ntile = k >> 4, n15 = k & 15;
    #pragma unroll
    for (int g = 0; g < 4; g++) {
        bf16x8 vh, vl;
        #pragma unroll
        for (int e = 0; e < 8; e++) {
            float v = wv[g * 8 + e];
            unsigned short h = f32_to_bf16(v);
            vh[e] = (short)h;
            vl[e] = (short)f32_to_bf16(v - bf16_to_f32(h));
        }
        int base = ((ntile * 64) + (g << 4) + n15) * 8;
        *(bf16x8*)&Wh[base] = vh;
        *(bf16x8*)&Wl[base] = vl;
    }
}

// ---------------------------------------------------------------------------
// Kernel 2: MFMA main — byte-identical to R0 (best measured 66.1/66.6 us).
// 256 blocks x 1024 threads (16 waves, 4 waves/SIMD).
// Block: 64 points (4 pt-tiles). Wave w: comps [w*64, w*64+64) (4 n-tiles).
// Per (pt,n) tile: 3x mfma_f32_16x16x32_bf16 (split-bf16: AhBh+AlBh+AhBl),
// exp2 on 4 C-regs, accumulate; DPP row_ror reduce over the 16 comp-lanes;
// LDS combine over waves.
// ---------------------------------------------------------------------------
__global__ __launch_bounds__(1024, 4) void gmm_main(
        const float* __restrict__ x,
        const unsigned short* __restrict__ Wh,
        const unsigned short* __restrict__ Wl,
        float* __restrict__ out) {
    const int tid  = threadIdx.x;
    const int lane = tid & 63;
    const int w    = __builtin_amdgcn_readfirstlane(tid >> 6);  // 0..15
    const int quad = lane >> 4;                                  // 0..3
    const int m15  = lane & 15;
    const int pbase = blockIdx.x * PTS;

    __shared__ bf16x8 fragA[8][64];          // [split*4+pt][lane], 8 KB
    __shared__ float  partial[NWAVE][PTS];   // 4 KB

    // ---- producer waves: build one (pt, split) fragment set ----
    if (w < 8) {
        const int pt    = w & 3;
        const int split = w >> 2;            // 0 = hi, 1 = lo
        float v[6];
        const float* xp = x + (pbase + pt * 16 + m15) * 6;
        #pragma unroll
        for (int i = 0; i < 6; i++) v[i] = xp[i];

        float f[8];
        if (quad == 0) {
            f[0]=v[0]*v[0]; f[1]=v[0]*v[1]; f[2]=v[0]*v[2]; f[3]=v[0]*v[3];
            f[4]=v[0]*v[4]; f[5]=v[0]*v[5]; f[6]=v[1]*v[1]; f[7]=v[1]*v[2];
        } else if (quad == 1) {
            f[0]=v[1]*v[3]; f[1]=v[1]*v[4]; f[2]=v[1]*v[5]; f[3]=v[2]*v[2];
            f[4]=v[2]*v[3]; f[5]=v[2]*v[4]; f[6]=v[2]*v[5]; f[7]=v[3]*v[3];
        } else if (quad == 2) {
            f[0]=v[3]*v[4]; f[1]=v[3]*v[5]; f[2]=v[4]*v[4]; f[3]=v[4]*v[5];
            f[4]=v[5]*v[5]; f[5]=v[0];      f[6]=v[1];      f[7]=v[2];
        } else {
            f[0]=v[3]; f[1]=v[4]; f[2]=v[5]; f[3]=1.0f;
            f[4]=0.0f; f[5]=0.0f; f[6]=0.0f; f[7]=0.0f;
        }

        bf16x8 frag;
        #pragma unroll
        for (int j = 0; j < 8; j++) {
            unsigned short h = f32_to_bf16(f[j]);
            frag[j] = (split == 0) ? (short)h
                                   : (short)f32_to_bf16(f[j] - bf16_to_f32(h));
        }
        fragA[w][lane] = frag;
    }
    __syncthreads();

    bf16x8 Ah[4], Al[4];
    #pragma unroll
    for (int pt = 0; pt < 4; pt++) {
        Ah[pt] = fragA[pt][lane];
        Al[pt] = fragA[4 + pt][lane];
    }

    // ---- MFMA loop over this wave's 4 n-tiles ----
    const bf16x8* WhF = (const bf16x8*)Wh + (w * NTPW) * 64;
    const bf16x8* WlF = (const bf16x8*)Wl + (w * NTPW) * 64;

    float esum[4][4];
    #pragma unroll
    for (int pt = 0; pt < 4; pt++)
        #pragma unroll
        for (int r = 0; r < 4; r++) esum[pt][r] = 0.0f;

    #pragma unroll
    for (int t = 0; t < NTPW; t++) {
        bf16x8 bh = WhF[t * 64 + lane];
        bf16x8 bl = WlF[t * 64 + lane];
        #pragma unroll
        for (int pt = 0; pt < 4; pt++) {
            f32x4 c = {0.0f, 0.0f, 0.0f, 0.0f};
            c = __builtin_amdgcn_mfma_f32_16x16x32_bf16(Ah[pt], bh, c, 0, 0, 0);
            c = __builtin_amdgcn_mfma_f32_16x16x32_bf16(Al[pt], bh, c, 0, 0, 0);
            c = __builtin_amdgcn_mfma_f32_16x16x32_bf16(Ah[pt], bl, c, 0, 0, 0);
            #pragma unroll
            for (int r = 0; r < 4; r++)
                esum[pt][r] += __builtin_amdgcn_exp2f(c[r]);
        }
    }

    // ---- reduce over the 16 comp-lanes (DPP row_ror rotate-adds) ----
    #pragma unroll
    for (int pt = 0; pt < 4; pt++)
        #pragma unroll
        for (int r = 0; r < 4; r++)
            esum[pt][r] = row16_sum(esum[pt][r]);

    if (m15 == 0) {
        #pragma unroll
        for (int pt = 0; pt < 4; pt++)
            #pragma unroll
            for (int r = 0; r < 4; r++)
                partial[w][pt * 16 + quad * 4 + r] = esum[pt][r];
    }
    __syncthreads();

    if (tid < PTS) {
        float S = 0.0f;
        #pragma unroll
        for (int c = 0; c < NWAVE; c++) S += partial[c][tid];
        const float LN2 = 0.6931471805599453f;
        out[pbase + tid] = LN2 * __builtin_amdgcn_logf(S);  // v_log_f32 = log2
    }
}

extern "C" void kernel_launch(void* const* d_in, const int* in_sizes, int n_in,
                              void* d_out, int out_size, void* d_ws, size_t ws_size,
                              hipStream_t stream) {
    const float* x       = (const float*)d_in[0];  // [B, 6]
    const float* means   = (const float*)d_in[1];  // [K, 6]
    const float* covs    = (const float*)d_in[2];  // [K, 6, 6]
    const float* weights = (const float*)d_in[3];  // [K]
    float* out = (float*)d_out;                    // [B]

    unsigned short* Wh = (unsigned short*)d_ws;            // 32768 x bf16 (64 KB)
    unsigned short* Wl = Wh + 32768;                       // 32768 x bf16 (64 KB)

    gmm_precompute<<<KCOMP / 64, 64, 0, stream>>>(means, covs, weights, Wh, Wl);
    gmm_main<<<BPTS / PTS, 1024, 0, stream>>>(x, Wh, Wl, out);
}